// Round 1
// baseline (231.704 us; speedup 1.0000x reference)
//
#include <hip/hip_runtime.h>
#include <math.h>

// Problem constants (from reference)
#define BB    8
#define HMC   2
#define HH    152
#define WWW   272
#define HW    (HH * WWW)      // 41344
#define EMBD  128
#define KOBJ  128
#define KG    8192
#define NID0  500
#define NID1  300

// d_ws layout:
//   float ws[0] pos_loss, [1] neg_loss, [2] num_pos, [3] num_wh, [4] num_off,
//         [5] mask_sum,  [6] nll0,     [7] nll1
//   int   ws[8] cnt0, ws[9] cnt1
//   int   idx0 at word 16 .. 16+KG, idx1 at 16+KG .. 16+2*KG
// total = (16 + 2*8192)*4 = 65,600 bytes  (well under typical ws_size)

__device__ __forceinline__ float wave_sum(float v) {
    #pragma unroll
    for (int o = 32; o > 0; o >>= 1) v += __shfl_down(v, o, 64);
    return v;
}

// ---------------- focal loss over hm_pred / hm ----------------
__global__ void focal_kernel(const float4* __restrict__ hp,
                             const float4* __restrict__ gt,
                             float* __restrict__ ws, int n4) {
    float pos = 0.f, neg = 0.f, cnt = 0.f;
    int stride = gridDim.x * blockDim.x;
    for (int i = blockIdx.x * blockDim.x + threadIdx.x; i < n4; i += stride) {
        float4 x = hp[i];
        float4 g = gt[i];
        float xs[4] = {x.x, x.y, x.z, x.w};
        float gs[4] = {g.x, g.y, g.z, g.w};
        #pragma unroll
        for (int j = 0; j < 4; ++j) {
            float s = 1.f / (1.f + expf(-xs[j]));
            s = fminf(fmaxf(s, 1e-4f), 1.f - 1e-4f);
            float gv = gs[j];
            if (gv == 1.f) {
                float om = 1.f - s;
                pos += logf(s) * om * om;
                cnt += 1.f;
            } else {
                float nw = 1.f - gv; nw = nw * nw; nw = nw * nw;
                neg += logf(1.f - s) * s * s * nw;
            }
        }
    }
    __shared__ float sm[3][4];
    float a = wave_sum(pos), b = wave_sum(neg), c = wave_sum(cnt);
    int lane = threadIdx.x & 63, wid = threadIdx.x >> 6;
    if (lane == 0) { sm[0][wid] = a; sm[1][wid] = b; sm[2][wid] = c; }
    __syncthreads();
    if (threadIdx.x == 0) {
        float s0 = 0, s1 = 0, s2 = 0;
        for (int w = 0; w < 4; ++w) { s0 += sm[0][w]; s1 += sm[1][w]; s2 += sm[2][w]; }
        atomicAdd(ws + 0, s0);
        atomicAdd(ws + 1, s1);
        atomicAdd(ws + 2, s2);
    }
}

// ---------------- wh / off L1 losses (single block) ----------------
__global__ void reg_kernel(const float* __restrict__ wh_pred,
                           const float* __restrict__ reg_pred,
                           const float* __restrict__ wh,
                           const float* __restrict__ reg,
                           const float* __restrict__ mask,
                           const int*   __restrict__ ind,
                           float* __restrict__ ws) {
    float nwh = 0.f, noff = 0.f, msum = 0.f;
    for (int t = threadIdx.x; t < BB * KOBJ; t += blockDim.x) {
        int b = t / KOBJ;
        float m = mask[t];
        int id = ind[t];
        const float* wp = wh_pred + (size_t)b * 2 * HW;
        const float* rp = reg_pred + (size_t)b * 2 * HW;
        float p0 = wp[id], p1 = wp[HW + id];
        float q0 = rp[id], q1 = rp[HW + id];
        float t0 = wh[t * 2], t1 = wh[t * 2 + 1];
        float r0 = reg[t * 2], r1 = reg[t * 2 + 1];
        nwh  += fabsf(p0 * m - t0 * m) + fabsf(p1 * m - t1 * m);
        noff += fabsf(q0 * m - r0 * m) + fabsf(q1 * m - r1 * m);
        msum += m;
    }
    __shared__ float sm[3][4];
    float a = wave_sum(nwh), b = wave_sum(noff), c = wave_sum(msum);
    int lane = threadIdx.x & 63, wid = threadIdx.x >> 6;
    if (lane == 0) { sm[0][wid] = a; sm[1][wid] = b; sm[2][wid] = c; }
    __syncthreads();
    if (threadIdx.x == 0) {
        float s0 = 0, s1 = 0, s2 = 0;
        for (int w = 0; w < 4; ++w) { s0 += sm[0][w]; s1 += sm[1][w]; s2 += sm[2][w]; }
        ws[3] = s0; ws[4] = s1; ws[5] = s2;   // single block: plain stores
    }
}

// ---------------- compaction of cls_id_map matches ----------------
__global__ void compact_kernel(const int* __restrict__ cmap,
                               int* __restrict__ cnt0, int* __restrict__ cnt1,
                               int* __restrict__ idx0, int* __restrict__ idx1, int n) {
    int stride = gridDim.x * blockDim.x;
    for (int i = blockIdx.x * blockDim.x + threadIdx.x; i < n; i += stride) {
        int v = cmap[i];
        if (v == 0) {
            int q = atomicAdd(cnt0, 1);
            if (q < KG) idx0[q] = i;
        } else if (v == 1) {
            int q = atomicAdd(cnt1, 1);
            if (q < KG) idx1[q] = i;
        }
    }
}

// ---------------- reid cross-entropy: one block per compacted entry ----------------
__global__ void reid_ce_kernel(const float* __restrict__ id_pred,
                               const int*   __restrict__ cls_tr_ids,
                               const float* __restrict__ Wc,
                               const float* __restrict__ bc,
                               int nid, float emb_scale,
                               const int* __restrict__ idxArr,
                               const int* __restrict__ cntPtr,
                               float* __restrict__ nll_out, int cls) {
    int cnt = *cntPtr;
    int m = cnt < KG ? cnt : KG;
    __shared__ float emb_s[EMBD];
    __shared__ float red[4];
    __shared__ float scale_s;
    __shared__ float tgt_logit;
    int tid = threadIdx.x, lane = tid & 63, wid = tid >> 6;

    for (int i = blockIdx.x; i < m; i += gridDim.x) {
        int p = idxArr[i];
        int b = p / HW, hw = p - b * HW;
        float f = 0.f;
        if (tid < EMBD) f = id_pred[((size_t)b * EMBD + tid) * HW + hw];
        float ss = wave_sum(f * f);
        if (lane == 0) red[wid] = ss;
        __syncthreads();
        if (tid == 0) {
            float s = red[0] + red[1] + red[2] + red[3];
            float nrm = fmaxf(sqrtf(s), 1e-12f);
            scale_s = emb_scale / nrm;
        }
        __syncthreads();
        if (tid < EMBD) emb_s[tid] = f * scale_s;
        __syncthreads();

        // per-thread logits (≤2 rows each)
        float lg[2];
        int nr = 0;
        float lmax = -INFINITY;
        for (int r = tid; r < nid; r += 256) {
            const float4* wr = (const float4*)(Wc + (size_t)r * EMBD);
            const float4* e4 = (const float4*)emb_s;
            float acc = bc[r];
            #pragma unroll
            for (int j = 0; j < EMBD / 4; ++j) {
                float4 w = wr[j]; float4 e = e4[j];
                acc += w.x * e.x + w.y * e.y + w.z * e.z + w.w * e.w;
            }
            lg[nr++] = acc;
            lmax = fmaxf(lmax, acc);
        }
        // block max
        #pragma unroll
        for (int o = 32; o > 0; o >>= 1) lmax = fmaxf(lmax, __shfl_down(lmax, o, 64));
        if (lane == 0) red[wid] = lmax;
        __syncthreads();
        if (tid == 0) red[0] = fmaxf(fmaxf(red[0], red[1]), fmaxf(red[2], red[3]));
        __syncthreads();
        float bmax = red[0];
        __syncthreads();   // red about to be reused

        int tgt = cls_tr_ids[((size_t)b * 2 + cls) * HW + hw];
        float se = 0.f;
        {
            int k = 0;
            for (int r = tid; r < nid; r += 256, ++k) {
                se += expf(lg[k] - bmax);
                if (r == tgt) tgt_logit = lg[k];
            }
        }
        se = wave_sum(se);
        if (lane == 0) red[wid] = se;
        __syncthreads();
        if (tid == 0) {
            float s = red[0] + red[1] + red[2] + red[3];
            float nll = bmax + logf(s) - tgt_logit;
            atomicAdd(nll_out, nll);
        }
        __syncthreads();   // protect shared reuse next iteration
    }
}

// ---------------- final scalar combine ----------------
__global__ void final_kernel(const float* __restrict__ wsf,
                             const float* __restrict__ sdet,
                             const float* __restrict__ sid,
                             float* __restrict__ out) {
    if (threadIdx.x == 0 && blockIdx.x == 0) {
        const int* wsi = (const int*)wsf;
        float pos = wsf[0], neg = wsf[1], npos = wsf[2];
        float hm_loss = (npos > 0.f) ? -(pos + neg) / fmaxf(npos, 1.f) : -neg;
        float wh_loss  = wsf[3] / (wsf[5] * 2.f + 1e-4f);
        float off_loss = wsf[4] / (wsf[5] * 2.f + 1e-4f);
        float reid = 0.f;
        {
            int c0 = wsi[8];
            float nv = (float)(c0 < KG ? c0 : KG);
            float ce = wsf[6] / fmaxf(nv, 1.f);
            if (c0 > 0) reid += ce / fmaxf((float)c0, 1.f);
        }
        {
            int c1 = wsi[9];
            float nv = (float)(c1 < KG ? c1 : KG);
            float ce = wsf[7] / fmaxf(nv, 1.f);
            if (c1 > 0) reid += ce / fmaxf((float)c1, 1.f);
        }
        float det = 1.0f * hm_loss + 0.1f * wh_loss + 1.0f * off_loss;
        float sd = sdet[0], si = sid[0];
        float loss = 0.5f * (expf(-sd) * det + expf(-si) * reid + sd + si);
        out[0] = loss;
        out[1] = hm_loss;
        out[2] = wh_loss;
        out[3] = off_loss;
        out[4] = reid;
    }
}

extern "C" void kernel_launch(void* const* d_in, const int* in_sizes, int n_in,
                              void* d_out, int out_size, void* d_ws, size_t ws_size,
                              hipStream_t stream) {
    const float* hm_pred   = (const float*)d_in[0];
    const float* wh_pred   = (const float*)d_in[1];
    const float* reg_pred  = (const float*)d_in[2];
    const float* id_pred   = (const float*)d_in[3];
    const float* hm        = (const float*)d_in[4];
    const float* wh        = (const float*)d_in[5];
    const float* reg       = (const float*)d_in[6];
    const float* reg_mask  = (const float*)d_in[7];
    const int*   ind       = (const int*)d_in[8];
    const int*   cls_map   = (const int*)d_in[9];
    const int*   cls_tr    = (const int*)d_in[10];
    const float* W0        = (const float*)d_in[11];
    const float* b0        = (const float*)d_in[12];
    const float* W1        = (const float*)d_in[13];
    const float* b1        = (const float*)d_in[14];
    const float* s_det     = (const float*)d_in[15];
    const float* s_id      = (const float*)d_in[16];

    float* wsf = (float*)d_ws;
    int*   wsi = (int*)d_ws;
    int*   idx0 = wsi + 16;
    int*   idx1 = wsi + 16 + KG;

    // zero the 16-word accumulator header each call
    hipMemsetAsync(d_ws, 0, 64, stream);

    const int N1  = BB * HMC * HW;   // 661504, divisible by 4
    const int n4  = N1 / 4;
    const int NBH = BB * HW;         // 330752

    focal_kernel<<<(n4 + 255) / 256, 256, 0, stream>>>(
        (const float4*)hm_pred, (const float4*)hm, wsf, n4);

    reg_kernel<<<1, 256, 0, stream>>>(wh_pred, reg_pred, wh, reg, reg_mask, ind, wsf);

    compact_kernel<<<512, 256, 0, stream>>>(cls_map, wsi + 8, wsi + 9, idx0, idx1, NBH);

    const float esc0 = (float)(sqrt(2.0) * log((double)NID0 - 1.0));
    const float esc1 = (float)(sqrt(2.0) * log((double)NID1 - 1.0));

    reid_ce_kernel<<<512, 256, 0, stream>>>(id_pred, cls_tr, W0, b0, NID0, esc0,
                                            idx0, wsi + 8, wsf + 6, 0);
    reid_ce_kernel<<<512, 256, 0, stream>>>(id_pred, cls_tr, W1, b1, NID1, esc1,
                                            idx1, wsi + 9, wsf + 7, 1);

    final_kernel<<<1, 64, 0, stream>>>(wsf, s_det, s_id, (float*)d_out);
}